// Round 1
// 82.912 us; speedup vs baseline: 1.0613x; 1.0613x over previous
//
#include <hip/hip_runtime.h>
#include <float.h>
#include <math.h>

#define B 128
#define D 128
#define N 3072      // 3*32*32
#define NP1 2048    // half-row sort size (pow2)
#define NZBLK 32    // zcos blocks (4 rows each, 512 threads)
#define TROW 64     // row-tiles (2 rows each)
#define NTILE (TROW*(TROW+1)/2)   // 2080 upper-tri 2x2 tiles
#define PAIR_BLOCKS (NTILE/8)     // 260 blocks x 8 waves, exact

__device__ __forceinline__ void cas(float& a, float& b, bool up) {
    float lo = fminf(a, b), hi = fmaxf(a, b);
    a = up ? lo : hi;
    b = up ? hi : lo;
}

// ---------------------------------------------------------------------------
// K1: blocks 0..255 sort one 2048-half of a row (bid>>1 = row, bid&1 = half).
// Half 0 sorted DESCENDING, half 1 ASCENDING -> concatenation is a valley
// bitonic sequence; FLT_MAX pads land in the unwritten tail (idx >= N).
// Blocks 256..287: zcos with inline L2-normalize (4 rows each).
// Block 288: zero out.
// ---------------------------------------------------------------------------
__global__ __launch_bounds__(512) void sort_half_kernel(const float* __restrict__ x,
                                                        const float* __restrict__ z,
                                                        float* __restrict__ xs,
                                                        float* __restrict__ zcos,
                                                        float* __restrict__ out) {
    __shared__ float smem[NP1];
    int tid = threadIdx.x;
    int bid = blockIdx.x;

    if (bid < 2 * B) {
        int row  = bid >> 1;
        int half = bid & 1;
        bool flip = (half == 0);          // half0 descending, half1 ascending
        int lbase = tid * 4;              // local index in [0, 2048)
        int gbase = half * NP1 + lbase;   // global index in row's 4096 space
        float v[4];

        if (gbase < N) {
            float4 t4 = *(const float4*)(x + (size_t)row * N + gbase);
            v[0] = t4.x; v[1] = t4.y; v[2] = t4.z; v[3] = t4.w;
        } else {
            v[0] = v[1] = v[2] = v[3] = FLT_MAX;
        }

        for (int k = 2; k <= NP1; k <<= 1) {
            int j = k >> 1;
            bool ub = (((lbase & k) == 0) != flip);

            if (j >= 256) {
                ((float4*)smem)[tid] = make_float4(v[0], v[1], v[2], v[3]);
                __syncthreads();
                for (; j >= 256; j >>= 1) {
                    #pragma unroll
                    for (int u = 0; u < 2; u++) {
                        int p = tid + u * 512;          // 1024 pairs per pass
                        int i = ((p & ~(j - 1)) << 1) | (p & (j - 1));
                        int pj = i | j;
                        float a = smem[i], b2 = smem[pj];
                        bool up = (((i & k) == 0) != flip);
                        if ((a > b2) == up) { smem[i] = b2; smem[pj] = a; }
                    }
                    __syncthreads();
                }
                float4 t4 = ((float4*)smem)[tid];
                v[0] = t4.x; v[1] = t4.y; v[2] = t4.z; v[3] = t4.w;
                __syncthreads();
            }

            for (; j >= 4; j >>= 1) {
                int lx = j >> 2;
                bool keep_lower = ((tid & lx) == 0);
                bool sel = (keep_lower == ub);
                #pragma unroll
                for (int r = 0; r < 4; r++) {
                    float p = __shfl_xor(v[r], lx, 64);
                    v[r] = sel ? fminf(v[r], p) : fmaxf(v[r], p);
                }
            }
            if (j == 2) {
                cas(v[0], v[2], ub);
                cas(v[1], v[3], ub);
                j >>= 1;
            }
            {
                bool upA = ((((lbase + 0) & k) == 0) != flip);
                bool upB = ((((lbase + 2) & k) == 0) != flip);
                cas(v[0], v[1], upA);
                cas(v[2], v[3], upB);
            }
        }

        if (gbase < N)
            *(float4*)(xs + (size_t)row * N + gbase) = make_float4(v[0], v[1], v[2], v[3]);
    } else if (bid < 2 * B + NZBLK) {
        float* inv_s = smem;           // [128] inverse norms
        {
            int row = tid >> 2;        // 4 threads per row
            int seg = tid & 3;         // 32 floats per segment
            const float4* zr = (const float4*)(z + row * D + seg * 32);
            float s = 0.f;
            #pragma unroll
            for (int u = 0; u < 8; u++) {
                float4 vv = zr[u];
                s += vv.x * vv.x + vv.y * vv.y + vv.z * vv.z + vv.w * vv.w;
            }
            s += __shfl_down(s, 2, 4);
            s += __shfl_down(s, 1, 4);
            if (seg == 0) inv_s[row] = 1.0f / fmaxf(sqrtf(s), 1e-12f);
        }
        __syncthreads();

        int gi = (bid - 2 * B) * 4 + (tid >> 7);
        int j  = tid & 127;
        const float4* zi = (const float4*)(z + gi * D);
        const float4* zj = (const float4*)(z + j * D);
        float dot = 0.f;
        #pragma unroll 8
        for (int k4 = 0; k4 < D / 4; k4++) {
            float4 a = zi[k4], b = zj[k4];
            dot += a.x * b.x + a.y * b.y + a.z * b.z + a.w * b.w;
        }
        zcos[gi * B + j] = dot * inv_s[gi] * inv_s[j];
    } else if (tid == 0) {
        out[0] = 0.f;
    }
}

// ---------------------------------------------------------------------------
// K2: final bitonic merge stage (k=4096, uniformly ascending) per row.
// Input: [2048 descending | 1024 ascending | 1024 implicit FLT_MAX] = bitonic.
// FLT_MAX pads regenerate on load and sort to the unwritten tail.
// ---------------------------------------------------------------------------
__global__ __launch_bounds__(1024) void merge_kernel(float* __restrict__ xs) {
    __shared__ float smem[4096];
    int tid = threadIdx.x;
    int row = blockIdx.x;
    int base = tid * 4;
    float v[4];

    if (base < N) {
        float4 t4 = *(const float4*)(xs + (size_t)row * N + base);
        v[0] = t4.x; v[1] = t4.y; v[2] = t4.z; v[3] = t4.w;
    } else {
        v[0] = v[1] = v[2] = v[3] = FLT_MAX;
    }

    ((float4*)smem)[tid] = make_float4(v[0], v[1], v[2], v[3]);
    __syncthreads();
    for (int j = 2048; j >= 256; j >>= 1) {
        #pragma unroll
        for (int u = 0; u < 2; u++) {
            int p = tid + u * 1024;
            int i = ((p & ~(j - 1)) << 1) | (p & (j - 1));
            int pj = i | j;
            float a = smem[i], b2 = smem[pj];
            if (a > b2) { smem[i] = b2; smem[pj] = a; }   // ascending
        }
        __syncthreads();
    }
    {
        float4 t4 = ((float4*)smem)[tid];
        v[0] = t4.x; v[1] = t4.y; v[2] = t4.z; v[3] = t4.w;
    }
    for (int j = 128; j >= 4; j >>= 1) {
        int lx = j >> 2;
        bool sel = ((tid & lx) == 0);
        #pragma unroll
        for (int r = 0; r < 4; r++) {
            float p = __shfl_xor(v[r], lx, 64);
            v[r] = sel ? fminf(v[r], p) : fmaxf(v[r], p);
        }
    }
    cas(v[0], v[2], true);
    cas(v[1], v[3], true);
    cas(v[0], v[1], true);
    cas(v[2], v[3], true);

    if (base < N)
        *(float4*)(xs + (size_t)row * N + base) = make_float4(v[0], v[1], v[2], v[3]);
}

// ---------------------------------------------------------------------------
// K3 pair (validated math): one 2x2 row-tile per wave. 260 blocks x 512
// threads (8 waves) = 2080 tiles exact; halves same-address atomic count.
// Diagonal tiles use weights {1,2,0,1}; off-diag weight 2 each.
// ---------------------------------------------------------------------------
__global__ __launch_bounds__(512) void pair_kernel(const float* __restrict__ xs,
                                                   const float* __restrict__ zcos,
                                                   float* __restrict__ out) {
    __shared__ float mx[2];
    __shared__ float partial[8];
    int tid = threadIdx.x;

    // diagonal max of zcos (max attained on diagonal), 2 waves
    if (tid < B) {
        float v = zcos[tid * (B + 1)];
        #pragma unroll
        for (int o = 32; o > 0; o >>= 1) v = fmaxf(v, __shfl_down(v, o, 64));
        if ((tid & 63) == 0) mx[tid >> 6] = v;
    }
    __syncthreads();
    float maxv = fmaxf(mx[0], mx[1]);

    int w = tid >> 6;                  // wave 0..7
    int lane = tid & 63;
    int T = blockIdx.x * 8 + w;        // tile index, always < NTILE

    // decode T -> (ti, tj), ti<=tj over TROW=64 (validated decode pattern)
    float ff = (float)(2 * TROW + 1);
    int ti = (int)((ff - sqrtf(ff * ff - 8.0f * (float)T)) * 0.5f);
    if (ti < 0) ti = 0;
    if (ti > TROW - 1) ti = TROW - 1;
    while ((ti + 1) * TROW - ((ti + 1) * ti) / 2 <= T) ti++;
    while (ti * TROW - (ti * (ti - 1)) / 2 > T) ti--;
    int tj = ti + (T - (ti * TROW - (ti * (ti - 1)) / 2));

    int r0 = 2 * ti, r1 = r0 + 1;
    int c0 = 2 * tj, c1 = c0 + 1;

    const float4* a0 = (const float4*)(xs + (size_t)r0 * N);
    const float4* a1 = (const float4*)(xs + (size_t)r1 * N);
    const float4* b0 = (const float4*)(xs + (size_t)c0 * N);
    const float4* b1 = (const float4*)(xs + (size_t)c1 * N);

    float s00 = 0.f, s01 = 0.f, s10 = 0.f, s11 = 0.f;
    #pragma unroll
    for (int u = 0; u < N / 4 / 64; u++) {          // 12 iterations
        int idx = lane + u * 64;
        float4 va0 = a0[idx], va1 = a1[idx];
        float4 vb0 = b0[idx], vb1 = b1[idx];
        s00 += fabsf(va0.x - vb0.x) + fabsf(va0.y - vb0.y)
             + fabsf(va0.z - vb0.z) + fabsf(va0.w - vb0.w);
        s01 += fabsf(va0.x - vb1.x) + fabsf(va0.y - vb1.y)
             + fabsf(va0.z - vb1.z) + fabsf(va0.w - vb1.w);
        s10 += fabsf(va1.x - vb0.x) + fabsf(va1.y - vb0.y)
             + fabsf(va1.z - vb0.z) + fabsf(va1.w - vb0.w);
        s11 += fabsf(va1.x - vb1.x) + fabsf(va1.y - vb1.y)
             + fabsf(va1.z - vb1.z) + fabsf(va1.w - vb1.w);
    }
    #pragma unroll
    for (int o = 32; o > 0; o >>= 1) {
        s00 += __shfl_down(s00, o, 64);
        s01 += __shfl_down(s01, o, 64);
        s10 += __shfl_down(s10, o, 64);
        s11 += __shfl_down(s11, o, 64);
    }
    if (lane == 0) {
        bool diag = (ti == tj);
        float w00 = diag ? 1.0f : 2.0f;
        float w01 = 2.0f;
        float w10 = diag ? 0.0f : 2.0f;
        float w11 = diag ? 1.0f : 2.0f;
        float inv_n = 1.0f / N;
        float d00 = s00 * inv_n - (maxv - zcos[r0 * B + c0]);
        float d01 = s01 * inv_n - (maxv - zcos[r0 * B + c1]);
        float d10 = s10 * inv_n - (maxv - zcos[r1 * B + c0]);
        float d11 = s11 * inv_n - (maxv - zcos[r1 * B + c1]);
        partial[w] = w00 * d00 * d00 + w01 * d01 * d01
                   + w10 * d10 * d10 + w11 * d11 * d11;
    }
    __syncthreads();
    if (tid == 0) {
        float blk = partial[0] + partial[1] + partial[2] + partial[3]
                  + partial[4] + partial[5] + partial[6] + partial[7];
        atomicAdd(out, blk * (1.0f / (B * B)));
    }
}

extern "C" void kernel_launch(void* const* d_in, const int* in_sizes, int n_in,
                              void* d_out, int out_size, void* d_ws, size_t ws_size,
                              hipStream_t stream) {
    const float* z = (const float*)d_in[0];   // [128,128]
    const float* x = (const float*)d_in[1];   // [128,3,32,32]
    float* out = (float*)d_out;               // [1]
    float* ws = (float*)d_ws;

    float* zcos = ws;                         // 16384 floats
    float* xs   = ws + 16384;                 // 393216 floats

    sort_half_kernel<<<2 * B + NZBLK + 1, 512, 0, stream>>>(x, z, xs, zcos, out);
    merge_kernel<<<B, 1024, 0, stream>>>(xs);
    pair_kernel<<<PAIR_BLOCKS, 512, 0, stream>>>(xs, zcos, out);
}